// Round 17
// baseline (87.709 us; speedup 1.0000x reference)
//
#include <hip/hip_runtime.h>

typedef float __attribute__((ext_vector_type(4))) f32x4;
typedef unsigned int u32;
typedef u32 __attribute__((ext_vector_type(2))) u32x2;

// OUT[n, c=j*8+k, h, w] = sum_{a,m,b} W[j,a,m,b,k] * T[n,(j+a-1)*4+m, (h-1)%28, taps]
//   T[n,cc,h,w] = x[n,cc,h,w] + x[n,cc+128,h,w]
//   gather taps per out w: b=2 <- w' = w (skip w==27), b=1 <- (w-1)%28, b=0 <- (w-2)%28
//     with the single exclusion w'==26 -/-> out 0 (handled as: skip only out w==0)
//
// R17 = R15 (tail-free, 1 barrier) minus its two measured poisons:
//   - PITCH 22 -> 23: odd pitch makes the b64 column reads hit distinct banks
//     (4q*23 mod 32 = 28q, distinct over q=0..6; <=2-way residual aliasing = free).
//     R15 had 8.0M conflict cycles (~13us/CU) from this alone.
//   - NO XCD swizzle: R15's swizzle put b2-adjacent blocks ~896 launch slots apart, so
//     the half-lines at 224B run boundaries never merged -> WRITE 141MB. R14 (adjacent
//     launch order, same 224B runs) merged to exactly 100.35MB. Linear order restores it.
// Structure: block = 448 thr (7 waves) = 32 out-ch-pairs x 2 rows x 7 w-quads;
//   (n, h-pair b2, channel-quarter qblk), qblk fastest; grid 128*14*4 = 7168;
//   4 blocks/CU (thread cap) = 28 waves/CU. LDS 5.15 KB. Stores natively contiguous:
//   lanes (q,s_) cover 224B per channel (rows h0,h0+1 adjacent in memory).
// Verified pieces: bf16-pair m-packing + v_dot2_f32_bf16 (absmax 0.5 since R7),
//   224B-run staging loads, zero-filled channel halo (0*W safe), R15 compute (passed).

#define PITCH 23

__device__ __forceinline__ u32 pack2bf(float lo, float hi) {
    u32 a = __float_as_uint(lo), b = __float_as_uint(hi);
    a = (a + 0x7FFFu + ((a >> 16) & 1u)) >> 16;   // RNE round to bf16
    b = (b + 0x7FFFu + ((b >> 16) & 1u)) >> 16;
    return a | (b << 16);
}

__device__ __forceinline__ float dot2bf(u32 t2, u32 w2, float acc) {
    asm("v_dot2_f32_bf16 %0, %1, %2, %0" : "+v"(acc) : "v"(t2), "v"(w2));
    return acc;
}

__global__ __launch_bounds__(448, 7) void fused_shift_conv(
    const float* __restrict__ x, const float* __restrict__ Wt, float* __restrict__ out)
{
    __shared__ __align__(8) u32 L[56 * PITCH];   // [2 rows][28 w'][20 pairs + pad] 5.15 KB

    const int bid  = blockIdx.x;                 // linear: qblk fastest, then b2, then n
    const int qblk = bid & 3;                    // channel quarter
    const int rest = bid >> 2;
    const int n    = rest / 14;
    const int b2   = rest - n * 14;
    const int h0   = b2 * 2;                     // output rows h0, h0+1
    const int J0   = qblk * 8;

    const int tid = threadIdx.x;
    const float* xn = x + (size_t)n * 200704;

    // ---- staging: 20 local pairs x 2 rows x 7 quads = 280 items (224B-run loads) ----
    if (tid < 280) {
        const int pl  = tid / 14;       // local pair 0..19 = (gl<<1)|mp
        const int rem = tid - pl * 14;
        const int row = rem / 7;        // input row 0..1 (h_src = h0-1+row)
        const int q   = rem - row * 7;  // quad 0..6
        const int gl  = pl >> 1;        // local group 0..9
        const int mp  = pl & 1;         // m-pair
        const int g   = J0 - 1 + gl;    // global group -1..32
        int hs = h0 - 1 + row; if (hs < 0) hs = 27;
        u32 wv0 = 0, wv1 = 0, wv2 = 0, wv3 = 0;     // OOB groups stay zero (0*W safe)
        if (g >= 0 && g <= 31) {
            const float* b0 = xn + (g * 4 + mp * 2) * 784 + hs * 28 + q * 4;
            const f32x4 lo0 = *(const f32x4*)b0;
            const f32x4 lo1 = *(const f32x4*)(b0 + 784);
            const f32x4 hi0 = *(const f32x4*)(b0 + 100352);
            const f32x4 hi1 = *(const f32x4*)(b0 + 100352 + 784);
            const f32x4 s0 = lo0 + hi0, s1 = lo1 + hi1;
            wv0 = pack2bf(s0[0], s1[0]);
            wv1 = pack2bf(s0[1], s1[1]);
            wv2 = pack2bf(s0[2], s1[2]);
            wv3 = pack2bf(s0[3], s1[3]);
        }
        // transposed write: dword (row*28 + w')*PITCH + pl, w' = q*4+e
        const int rb = (row * 28 + q * 4) * PITCH + pl;
        L[rb            ] = wv0;
        L[rb + PITCH    ] = wv1;
        L[rb + 2 * PITCH] = wv2;
        L[rb + 3 * PITCH] = wv3;
    }

    // ---- thread mapping: tid = po*14 + s_*7 + q ----
    const int po  = tid / 14;           // output channel pair 0..31
    const int r14 = tid - po * 14;
    const int s_  = r14 / 7;            // output row h0 + s_
    const int q   = r14 - s_ * 7;       // w quad 0..6
    const int jl  = po >> 2;            // local group 0..7
    const int kp  = po & 3;             // k-pair

    // ---- weights: w2[ch2][a][mp][b] bf16-pair packed along m ----
    u32 w2[2][3][2][3];
    {
        const float* wpb = Wt + (J0 + jl) * 288 + kp * 2;   // strides 288/96/24/8/1
        #pragma unroll
        for (int c = 0; c < 2; ++c)
            #pragma unroll
            for (int a = 0; a < 3; ++a)
                #pragma unroll
                for (int mp = 0; mp < 2; ++mp)
                    #pragma unroll
                    for (int b = 0; b < 3; ++b)
                        w2[c][a][mp][b] = pack2bf(wpb[a*96 + (2*mp  )*24 + b*8 + c],
                                                  wpb[a*96 + (2*mp+1)*24 + b*8 + c]);
    }

    __syncthreads();                    // the only barrier

    // ---- compute: per w-row 3 ds_read_b64 + up to 36 dot2 (gather over 3 taps) ----
    float acc[2][4];
    #pragma unroll
    for (int c = 0; c < 2; ++c)
        #pragma unroll
        for (int e = 0; e < 4; ++e) acc[c][e] = 0.f;

    const int colb = (s_ * 28) * PITCH + 2 * jl;
    #pragma unroll
    for (int i = 0; i < 6; ++i) {
        int wr = q * 4 - 2 + i;                       // w' = 4q-2+i mod 28
        wr = (wr < 0) ? wr + 28 : (wr >= 28 ? wr - 28 : wr);
        const u32* rp = &L[colb + wr * PITCH];
        const u32x2 t01 = *(const u32x2*)rp;          // a=0: mp0, mp1
        const u32x2 t23 = *(const u32x2*)(rp + 2);    // a=1
        const u32x2 t45 = *(const u32x2*)(rp + 4);    // a=2
        const u32 Td[6] = {t01[0], t01[1], t23[0], t23[1], t45[0], t45[1]};

        // b=0 tap: out e = i  (skip: out w==0 i.e. i==0 && q==0)
        if (i < 4) {
            if (!(i == 0 && q == 0)) {
                #pragma unroll
                for (int c = 0; c < 2; ++c)
                    #pragma unroll
                    for (int a = 0; a < 3; ++a)
                        #pragma unroll
                        for (int mp = 0; mp < 2; ++mp)
                            acc[c][i] = dot2bf(Td[a*2+mp], w2[c][a][mp][0], acc[c][i]);
            }
        }
        // b=1 tap: out e = i-1 (always)
        if (i >= 1 && i <= 4) {
            #pragma unroll
            for (int c = 0; c < 2; ++c)
                #pragma unroll
                for (int a = 0; a < 3; ++a)
                    #pragma unroll
                    for (int mp = 0; mp < 2; ++mp)
                        acc[c][i-1] = dot2bf(Td[a*2+mp], w2[c][a][mp][1], acc[c][i-1]);
        }
        // b=2 tap: out e = i-2  (skip: out w==27 i.e. i==5 && q==6)
        if (i >= 2) {
            if (!(i == 5 && q == 6)) {
                #pragma unroll
                for (int c = 0; c < 2; ++c)
                    #pragma unroll
                    for (int a = 0; a < 3; ++a)
                        #pragma unroll
                        for (int mp = 0; mp < 2; ++mp)
                            acc[c][i-2] = dot2bf(Td[a*2+mp], w2[c][a][mp][2], acc[c][i-2]);
            }
        }
    }

    // ---- stores: lanes (q,s_) fastest -> 224 B contiguous per channel ----
    const int c0 = (J0 + jl) * 8 + kp * 2;
    float* op = out + (size_t)n * 200704 + (size_t)c0 * 784 + (h0 + s_) * 28 + q * 4;
    f32x4 o0, o1;
    o0.x = acc[0][0]; o0.y = acc[0][1]; o0.z = acc[0][2]; o0.w = acc[0][3];
    o1.x = acc[1][0]; o1.y = acc[1][1]; o1.z = acc[1][2]; o1.w = acc[1][3];
    *(f32x4*)op = o0;
    *(f32x4*)(op + 784) = o1;
}

extern "C" void kernel_launch(void* const* d_in, const int* in_sizes, int n_in,
                              void* d_out, int out_size, void* d_ws, size_t ws_size,
                              hipStream_t stream) {
    const float* x  = (const float*)d_in[0];   // (128,256,28,28) f32
    const float* Wt = (const float*)d_in[1];   // (32,3,4,3,8)   f32
    float* out      = (float*)d_out;           // (128,256,28,28) f32

    const int nbatch = in_sizes[0] / 200704;   // 128
    // grid = n x 14 h-pairs x 4 channel-quarters = 7168, LINEAR order (qblk fastest)
    fused_shift_conv<<<nbatch * 56, 448, 0, stream>>>(x, Wt, out);
}

// Round 18
// 49.928 us; speedup vs baseline: 1.7567x; 1.7567x over previous
//
#include <hip/hip_runtime.h>

typedef float __attribute__((ext_vector_type(4))) f32x4;
typedef unsigned int u32;
typedef u32 __attribute__((ext_vector_type(4))) u32x4;

// OUT[n, c=j*8+k, h, w] = sum_{a,m,b} W[j,a,m,b,k] * T[n,(j+a-1)*4+m, (h-1)%28, (w+b-2)%28]
//   T[n,cc,h,w] = x[n,cc,h,w] + x[n,cc+128,h,w]
//   (j+a-1) outside [0,32) -> zero; (w+b-1) outside [0,28) -> zero (w unfold pad)
//
// R18 = R11 verbatim (best measured: 50.31 us, FETCH ~80MB, WRITE == 100.35MB exact,
//   conflicts 0.6M, no pipe >35%). Reconfirmation run before declaring the structural
//   plateau. Full negative-result ledger for the residual vs the 33us naive-BW floor:
//   occupancy up = flat (R9), fewer barriers = worse (R12), more contexts = flat/worse
//   (R13/R14), longer store runs via 1-row blocks = worse (R13), tail-free per-thread
//   stores = write amplification +40-60MB (R15/R17), cross-unit register pipelining =
//   scratch spills (R3/R16), DMA+counted vmcnt = races/serialization (R4/R5).
//   Empirical write law: stores must be a dedicated post-barrier burst covering a
//   >=224B-per-channel slab, lane-contiguous within each instruction, launch-adjacent
//   blocks covering adjacent slabs -> exact-sized HBM writes.
// Structure: block = (n, h-pair), 512 threads; slice s_=tid>>8 computes row h0+s_;
//   thread owns output channel c = j*8+k. bf16-pair m-packed LDS + v_dot2_f32_bf16
//   f32-accum compute (absmax 0.5 since R7); quad-slot swizzle q^(g&7) (conflict-free,
//   R2); 224B-run coalesced staging; 2-round 128-ch LDS-routed tail with 224B-run
//   stores. LDS 30.7KB -> 4 blocks/CU.

__device__ __forceinline__ u32 pack2bf(float lo, float hi) {
    u32 a = __float_as_uint(lo), b = __float_as_uint(hi);
    a = (a + 0x7FFFu + ((a >> 16) & 1u)) >> 16;   // RNE round to bf16
    b = (b + 0x7FFFu + ((b >> 16) & 1u)) >> 16;
    return a | (b << 16);
}

__device__ __forceinline__ float dot2bf(u32 t2, u32 w2, float acc) {
    asm("v_dot2_f32_bf16 %0, %1, %2, %0" : "+v"(acc) : "v"(t2), "v"(w2));
    return acc;
}

__global__ __launch_bounds__(512, 8) void fused_shift_conv(
    const float* __restrict__ x, const float* __restrict__ Wt, float* __restrict__ out)
{
    // input: 2 rows x 2048 dwords (16 KB, first 4096 dwords)
    // output rounds reuse the whole buffer: 128 ch x 60 floats = 30.7 KB
    __shared__ __align__(16) u32 L[7680];

    const int tid = threadIdx.x;
    const int blk = blockIdx.x;
    const int n   = blk / 14;
    const int b2  = blk - n * 14;
    const int h0  = b2 * 2;                 // output rows h0, h0+1 (no wrap; 2*13+1=27)

    const float* xn = x + (size_t)n * 200704;

    // ---- staging: 64 ch-pairs x 2 input rows x 7 quads = 896 items ----
    // consecutive items walk (row,q) within a pair -> 224 B contiguous runs.
    #pragma unroll
    for (int it = 0; it < 2; ++it) {
        const int f = tid + it * 512;
        if (f < 896) {
            const int p     = f / 14;       // channel pair 0..63 (ch 2p, 2p+1)
            const int rem14 = f - p * 14;
            const int row   = rem14 / 7;    // input row index 0..1
            const int q     = rem14 - row * 7;
            int hs = h0 - 1 + row;          // wraps only when h0==0 && row==0
            hs = hs < 0 ? 27 : hs;
            const float* b0 = xn + (2 * p) * 784 + hs * 28 + q * 4;
            const f32x4 l0 = *(const f32x4*)b0;                  // ch 2p,   low half
            const f32x4 l1 = *(const f32x4*)(b0 + 784);          // ch 2p+1, low half
            const f32x4 u0 = *(const f32x4*)(b0 + 100352);       // high halves
            const f32x4 u1 = *(const f32x4*)(b0 + 784 + 100352);
            const f32x4 s0 = l0 + u0, s1 = l1 + u1;
            u32x4 wv;
            #pragma unroll
            for (int e = 0; e < 4; ++e) wv[e] = pack2bf(s0[e], s1[e]);
            const int sw = (p >> 1) & 7;    // g = p>>1
            *(u32x4*)&L[row * 2048 + p * 32 + ((q ^ sw) << 2)] = wv;
        }
    }

    // ---- per-thread weights: slice s_ computes row h0+s_, thread owns c = j*8+k ----
    const int t  = tid & 255;
    const int s_ = tid >> 8;                // slice 0/1
    const int j = t >> 3, k = t & 7;
    u32 w2[3][2][3];                        // [a][m-pair][tap], bf16-pair packed
    {
        const float* wp = Wt + j * 288 + k; // W[j,a,m,b,k] strides 288/96/24/8/1
        #pragma unroll
        for (int a = 0; a < 3; ++a)
            #pragma unroll
            for (int m2 = 0; m2 < 2; ++m2)
                #pragma unroll
                for (int bb = 0; bb < 3; ++bb)
                    w2[a][m2][bb] = pack2bf(wp[a*96 + (2*m2  )*24 + bb*8],
                                            wp[a*96 + (2*m2+1)*24 + bb*8]);
    }
    if (j == 0) {
        #pragma unroll
        for (int m2 = 0; m2 < 2; ++m2)
            #pragma unroll
            for (int bb = 0; bb < 3; ++bb) w2[0][m2][bb] = 0u;
    }
    if (j == 31) {
        #pragma unroll
        for (int m2 = 0; m2 < 2; ++m2)
            #pragma unroll
            for (int bb = 0; bb < 3; ++bb) w2[2][m2][bb] = 0u;
    }

    // ---- hoisted output-stage indices (round-invariant) ----
    // round: 128 local ch x 2 rows x 7 quads = 1792 f4 items; 4 iterations of 512
    int o_lds[4], o_glb[4];                 // LDS dword offset, global float offset
    #pragma unroll
    for (int it = 0; it < 4; ++it) {
        const int fo  = tid + it * 512;
        const int chl = fo / 14;            // local channel 0..127 (fo<1792)
        const int rem = fo - chl * 14;      // f4 within the 56-float (2-row) run
        o_lds[it] = chl * 60 + rem * 4;
        o_glb[it] = chl * 784 + h0 * 28 + rem * 4;
    }

    __syncthreads();

    // ---- compute (verified body): 42 ds_read_b128 + ~492 dot2 ----
    const u32* Bs = L + s_ * 2048;
    float acc[28];
    #pragma unroll
    for (int w = 0; w < 28; ++w) acc[w] = 0.f;

    #pragma unroll
    for (int a = 0; a < 3; ++a) {
        int g = j + a - 1;
        g = g < 0 ? 0 : (g > 31 ? 31 : g);  // weights already zeroed for OOB
        const int s = g & 7;
        #pragma unroll
        for (int m2 = 0; m2 < 2; ++m2) {
            const int rowd = (g * 2 + m2) * 32;
            const u32 t2 = w2[a][m2][2], t1 = w2[a][m2][1], t0 = w2[a][m2][0];
            #pragma unroll
            for (int qb = 0; qb < 7; ++qb) {
                const u32x4 v = *(const u32x4*)&Bs[rowd + ((qb ^ s) << 2)];
                #pragma unroll
                for (int e = 0; e < 4; ++e) {
                    const int wp_ = qb * 4 + e;                              // source col w'
                    if (wp_ != 27) acc[wp_] = dot2bf(v[e], t2, acc[wp_]);    // b=2 tap
                    acc[(wp_ + 1) % 28] = dot2bf(v[e], t1, acc[(wp_ + 1) % 28]); // b=1
                    if (wp_ != 26) acc[(wp_ + 2) % 28] = dot2bf(v[e], t0, acc[(wp_ + 2) % 28]); // b=0
                }
            }
        }
    }

    // ---- output: 2 rounds of 128 channels via LDS, contiguous 224 B stores ----
    float* Lf = (float*)L;                  // input region dead after compute
    float* outn = out + (size_t)n * 200704;
    #pragma unroll
    for (int c = 0; c < 2; ++c) {
        __syncthreads();                    // compute done / prev round reads done
        if ((j >> 4) == c) {
            const int oc = (j & 15) * 8 + k;         // local channel 0..127
            float* dst = Lf + oc * 60 + s_ * 28;     // pitch 60 floats, 16B-aligned
            #pragma unroll
            for (int qq = 0; qq < 7; ++qq) {
                f32x4 o;
                o.x = acc[qq * 4 + 0];
                o.y = acc[qq * 4 + 1];
                o.z = acc[qq * 4 + 2];
                o.w = acc[qq * 4 + 3];
                *(f32x4*)(dst + qq * 4) = o;
            }
        }
        __syncthreads();
        float* outc = outn + (size_t)c * 128 * 784;
        #pragma unroll
        for (int it = 0; it < 4; ++it) {
            if (tid + it * 512 < 1792) {
                const f32x4 v = *(const f32x4*)(Lf + o_lds[it]);
                *(f32x4*)(outc + o_glb[it]) = v;
            }
        }
    }
}

extern "C" void kernel_launch(void* const* d_in, const int* in_sizes, int n_in,
                              void* d_out, int out_size, void* d_ws, size_t ws_size,
                              hipStream_t stream) {
    const float* x  = (const float*)d_in[0];   // (128,256,28,28) f32
    const float* Wt = (const float*)d_in[1];   // (32,3,4,3,8)   f32
    float* out      = (float*)d_out;           // (128,256,28,28) f32

    const int nbatch = in_sizes[0] / 200704;   // 128
    fused_shift_conv<<<nbatch * 14, 512, 0, stream>>>(x, Wt, out);  // (n, h-pair)
}